// Round 13
// baseline (122.572 us; speedup 1.0000x reference)
//
#include <hip/hip_runtime.h>
#include <hip/hip_bf16.h>

// IDWT2D db4, periodized. Input x: [64][256][256][16] f32 (cA|cH|cV|cD x 4ch),
// output: [64][512][512][4] f32.
//
// R12 = R11 with: RJ=8 (2048 blocks -> backfill/tail smoothing), pass1
// layout reverted to R10's thalf=t>>8 (kills the 1e6 LDS write conflicts
// R11's paired layout introduced), and all math on ext_vector f32x4 with
// __builtin_elementwise_fma so the compiler can form v_pk_fma_f32
// (scalar fmaf chains block packing; VALU pipe ~30 -> ~18 us).
// Structure: 1-j-row chunks, bf16-packed double-buffered LDS (16 KB),
// register sliding window pass1, pass2 thread = output column (dense f4
// stores), lgkm-only barrier.

#define N 256
#define RJ 8

typedef float f32x4 __attribute__((ext_vector_type(4)));

// lgkm-only barrier: LDS producer-consumer sync without vmcnt drain.
#define LGKM_BARRIER()                                   \
  do {                                                   \
    asm volatile("s_waitcnt lgkmcnt(0)" ::: "memory");   \
    __builtin_amdgcn_s_barrier();                        \
    asm volatile("" ::: "memory");                       \
  } while (0)

__device__ __forceinline__ f32x4 fma4v(const f32x4 acc, const float s,
                                       const f32x4 a) {
  const f32x4 sv = {s, s, s, s};
  return __builtin_elementwise_fma(a, sv, acc);
}

__device__ __forceinline__ uint2 pack_bf16x4(const f32x4 v) {
  __hip_bfloat162 lo = __float22bfloat162_rn(make_float2(v.x, v.y));
  __hip_bfloat162 hi = __float22bfloat162_rn(make_float2(v.z, v.w));
  uint2 r;
  r.x = *reinterpret_cast<const unsigned int*>(&lo);
  r.y = *reinterpret_cast<const unsigned int*>(&hi);
  return r;
}

__device__ __forceinline__ f32x4 unpack_bf16x4(const uint2 u) {
  f32x4 r;
  r.x = __uint_as_float(u.x << 16);
  r.y = __uint_as_float(u.x & 0xffff0000u);
  r.z = __uint_as_float(u.y << 16);
  r.w = __uint_as_float(u.y & 0xffff0000u);
  return r;
}

__global__ __launch_bounds__(512, 4) void idwt2_sep12_kernel(
    const float* __restrict__ x, float* __restrict__ out) {
  constexpr float LO[8] = {
      0.23037781330885523f,  0.7148465705525415f,  0.6308807679295904f,
      -0.02798376941698385f, -0.18703481171888114f, 0.030841381835986965f,
      0.032883011666982945f, -0.010597401784997278f};
  constexpr float HIW[8] = {
      -0.010597401784997278f, -0.032883011666982945f, 0.030841381835986965f,
      0.18703481171888114f,  -0.02798376941698385f,  -0.6308807679295904f,
      0.7148465705525415f,   -0.23037781330885523f};
  const float Lw[2][4] = {{LO[6], LO[4], LO[2], LO[0]},
                          {LO[7], LO[5], LO[3], LO[1]}};
  const float Hw[2][4] = {{HIW[6], HIW[4], HIW[2], HIW[0]},
                          {HIW[7], HIW[5], HIW[3], HIW[1]}};

  // [buf][parity p][lo/hi][col] packed bf16x4 = 16 KB
  __shared__ uint2 I[2][2][2][N];

  const int t = threadIdx.x;
  const int bx = blockIdx.x;
  const int b = bx >> 5;           // 32 consecutive blocks per batch
  const int r0 = (bx & 31) * RJ;

  const f32x4* xb = reinterpret_cast<const f32x4*>(x) + (size_t)b * N * N * 4;
  f32x4* ob = reinterpret_cast<f32x4*>(out) + (size_t)b * (2 * N) * (2 * N);

  // ---- Pass1 identity: column + lo/hi half (R10 layout) ----
  const int tcol = t & (N - 1);
  const int thalf = t >> 8;  // 0: lo from (cA,cH); 1: hi from (cV,cD)
  const f32x4* xcolp = xb + (size_t)tcol * 4 + thalf * 2;

  f32x4 wA[4], wB[4], nA, nB;
  auto ldrow = [&](int lr, f32x4& A, f32x4& B) {
    const int gr = (r0 + lr) & (N - 1);
    A = xcolp[(size_t)gr * (N * 4)];
    B = xcolp[(size_t)gr * (N * 4) + 1];
  };

  // y-filter local j-row j into I[buf]; window slot (j+sy)&3 holds row j+sy.
  auto p1 = [&](int j, int buf) {
    f32x4 v0 = {0.f, 0.f, 0.f, 0.f};
    f32x4 v1 = {0.f, 0.f, 0.f, 0.f};
#pragma unroll
    for (int sy = 0; sy < 4; ++sy) {
      const f32x4 a = wA[(j + sy) & 3];
      const f32x4 bb = wB[(j + sy) & 3];
      v0 = fma4v(v0, Lw[0][sy], a);
      v0 = fma4v(v0, Hw[0][sy], bb);
      v1 = fma4v(v1, Lw[1][sy], a);
      v1 = fma4v(v1, Hw[1][sy], bb);
    }
    I[buf][0][thalf][tcol] = pack_bf16x4(v0);
    I[buf][1][thalf][tcol] = pack_bf16x4(v1);
  };

  // Prologue: window rows 0..3, prefetch row 4; p1(0) -> I[0].
#pragma unroll
  for (int m = 0; m < 4; ++m) ldrow(m, wA[m], wB[m]);
  ldrow(4, nA, nB);
  p1(0, 0);
  wA[0] = nA;  // row 4 -> slot 0 (row 0 dead)
  wB[0] = nB;
  ldrow(5, nA, nB);
  LGKM_BARRIER();

  // ---- Pass2 identity: output column t (dense stores) ----
  const int jx = t >> 1;
  const int q = t & 1;
  float Lq[4], Hq[4];
#pragma unroll
  for (int s = 0; s < 4; ++s) {
    Lq[s] = q ? Lw[1][s] : Lw[0][s];
    Hq[s] = q ? Hw[1][s] : Hw[0][s];
  }

#pragma unroll
  for (int c = 0; c < RJ; ++c) {
    const int buf = c & 1;

    // ---- Pass2: x-filter j-row c from I[buf] ----
    f32x4 o0 = {0.f, 0.f, 0.f, 0.f};
    f32x4 o1 = {0.f, 0.f, 0.f, 0.f};
#pragma unroll
    for (int s = 0; s < 4; ++s) {
      const int xc = (jx + s) & (N - 1);
      const f32x4 l0 = unpack_bf16x4(I[buf][0][0][xc]);
      const f32x4 h0 = unpack_bf16x4(I[buf][0][1][xc]);
      const f32x4 l1 = unpack_bf16x4(I[buf][1][0][xc]);
      const f32x4 h1 = unpack_bf16x4(I[buf][1][1][xc]);
      o0 = fma4v(o0, Lq[s], l0);
      o0 = fma4v(o0, Hq[s], h0);
      o1 = fma4v(o1, Lq[s], l1);
      o1 = fma4v(o1, Hq[s], h1);
    }
    const int jy = r0 + c;
    f32x4* po = ob + (size_t)(2 * jy) * (2 * N) + t;
    po[0] = o0;
    po[2 * N] = o1;

    if (c < RJ - 1) {
      // ---- Pass1: j-row c+1 (uses window rows c+1..c+4) ----
      p1(c + 1, buf ^ 1);
      // Slide: row c+5 (prefetched, vmcnt-waited here) -> slot (c+1)&3;
      // issue prefetch of row c+6 (stays in flight across the barrier).
      if (c <= RJ - 3) {
        wA[(c + 1) & 3] = nA;
        wB[(c + 1) & 3] = nB;
      }
      if (c <= RJ - 4) ldrow(c + 6, nA, nB);
      LGKM_BARRIER();
    }
  }
}

extern "C" void kernel_launch(void* const* d_in, const int* in_sizes, int n_in,
                              void* d_out, int out_size, void* d_ws,
                              size_t ws_size, hipStream_t stream) {
  const float* x = reinterpret_cast<const float*>(d_in[0]);
  float* out = reinterpret_cast<float*>(d_out);
  const int grid = 64 * (N / RJ);  // 2048 blocks
  idwt2_sep12_kernel<<<grid, 512, 0, stream>>>(x, out);
}

// Round 14
// 116.069 us; speedup vs baseline: 1.0560x; 1.0560x over previous
//
#include <hip/hip_runtime.h>
#include <hip/hip_bf16.h>

// IDWT2D db4, periodized. Input x: [64][256][256][16] f32 (cA|cH|cV|cD x 4ch),
// output: [64][512][512][4] f32.
//
// R13 = best-known structure (RJ=16, f32 32KB double-buffered LDS, dense
// stores, lgkm-only barrier, pk-fma) + PREFETCH DISTANCE 3:
// - prefetch ring pfA/pfB[3] holds 3 in-flight rows (f32; packing on arrival
//   would force the vmcnt wait and defeat the prefetch),
// - register window packed to bf16 (16 VGPR vs 32) to keep total <=64 VGPR
//   (no occupancy cliff; 4 blocks/CU). Pack happens at consume time, 3
//   row-steps after issue -> memory-queue delay (~1 row-step) fully covered.
// Mechanism: marginal-BW evidence (R12: +59 MB FETCH -> +10 us) says the
// per-row-step memory service time ~= one row-step; distance-1 prefetch sat
// exactly at the edge, exposing queue jitter as per-step stalls.

#define N 256
#define RJ 16

typedef float f32x4 __attribute__((ext_vector_type(4)));

// lgkm-only barrier: LDS producer-consumer sync without vmcnt drain.
#define LGKM_BARRIER()                                   \
  do {                                                   \
    asm volatile("s_waitcnt lgkmcnt(0)" ::: "memory");   \
    __builtin_amdgcn_s_barrier();                        \
    asm volatile("" ::: "memory");                       \
  } while (0)

__device__ __forceinline__ f32x4 fma4v(const f32x4 acc, const float s,
                                       const f32x4 a) {
  const f32x4 sv = {s, s, s, s};
  return __builtin_elementwise_fma(a, sv, acc);
}

__device__ __forceinline__ uint2 pack_bf16x4(const f32x4 v) {
  __hip_bfloat162 lo = __float22bfloat162_rn(make_float2(v.x, v.y));
  __hip_bfloat162 hi = __float22bfloat162_rn(make_float2(v.z, v.w));
  uint2 r;
  r.x = *reinterpret_cast<const unsigned int*>(&lo);
  r.y = *reinterpret_cast<const unsigned int*>(&hi);
  return r;
}

__device__ __forceinline__ f32x4 unpack_bf16x4(const uint2 u) {
  f32x4 r;
  r.x = __uint_as_float(u.x << 16);
  r.y = __uint_as_float(u.x & 0xffff0000u);
  r.z = __uint_as_float(u.y << 16);
  r.w = __uint_as_float(u.y & 0xffff0000u);
  return r;
}

__global__ __launch_bounds__(512, 4) void idwt2_sep13_kernel(
    const float* __restrict__ x, float* __restrict__ out) {
  constexpr float LO[8] = {
      0.23037781330885523f,  0.7148465705525415f,  0.6308807679295904f,
      -0.02798376941698385f, -0.18703481171888114f, 0.030841381835986965f,
      0.032883011666982945f, -0.010597401784997278f};
  constexpr float HIW[8] = {
      -0.010597401784997278f, -0.032883011666982945f, 0.030841381835986965f,
      0.18703481171888114f,  -0.02798376941698385f,  -0.6308807679295904f,
      0.7148465705525415f,   -0.23037781330885523f};
  const float Lw[2][4] = {{LO[6], LO[4], LO[2], LO[0]},
                          {LO[7], LO[5], LO[3], LO[1]}};
  const float Hw[2][4] = {{HIW[6], HIW[4], HIW[2], HIW[0]},
                          {HIW[7], HIW[5], HIW[3], HIW[1]}};

  // [buf][parity p][lo/hi][col] f32x4 = 32 KB
  __shared__ f32x4 I[2][2][2][N];

  const int t = threadIdx.x;
  const int bx = blockIdx.x;
  const int b = bx >> 4;           // 16 consecutive blocks per batch
  const int r0 = (bx & 15) * RJ;

  const f32x4* xb = reinterpret_cast<const f32x4*>(x) + (size_t)b * N * N * 4;
  f32x4* ob = reinterpret_cast<f32x4*>(out) + (size_t)b * (2 * N) * (2 * N);

  // ---- Pass1 identity: column + lo/hi half ----
  const int tcol = t & (N - 1);
  const int thalf = t >> 8;  // 0: lo from (cA,cH); 1: hi from (cV,cD)
  const f32x4* xcolp = xb + (size_t)tcol * 4 + thalf * 2;

  uint2 wPA[4], wPB[4];  // bf16-packed 4-row window
  f32x4 pfA[3], pfB[3];  // f32 prefetch ring (3 rows in flight)

  auto ldrow = [&](int lr, f32x4& A, f32x4& B) {
    const int gr = (r0 + lr) & (N - 1);
    A = xcolp[(size_t)gr * (N * 4)];
    B = xcolp[(size_t)gr * (N * 4) + 1];
  };

  // y-filter local j-row j into I[buf]; window slot (j+sy)&3 holds row j+sy.
  auto p1 = [&](int j, int buf) {
    f32x4 v0 = {0.f, 0.f, 0.f, 0.f};
    f32x4 v1 = {0.f, 0.f, 0.f, 0.f};
#pragma unroll
    for (int sy = 0; sy < 4; ++sy) {
      const f32x4 a = unpack_bf16x4(wPA[(j + sy) & 3]);
      const f32x4 bb = unpack_bf16x4(wPB[(j + sy) & 3]);
      v0 = fma4v(v0, Lw[0][sy], a);
      v0 = fma4v(v0, Hw[0][sy], bb);
      v1 = fma4v(v1, Lw[1][sy], a);
      v1 = fma4v(v1, Hw[1][sy], bb);
    }
    I[buf][0][thalf][tcol] = v0;
    I[buf][1][thalf][tcol] = v1;
  };

  // Prologue: rows 0..3 -> packed window; row 4 -> slot 0 after p1(0);
  // issue prefetch rows 5,6,7 (ring slot = row % 3).
#pragma unroll
  for (int m = 0; m < 4; ++m) {
    f32x4 A, B;
    ldrow(m, A, B);
    wPA[m] = pack_bf16x4(A);
    wPB[m] = pack_bf16x4(B);
  }
  {
    f32x4 A, B;
    ldrow(4, A, B);
    p1(0, 0);
    wPA[0] = pack_bf16x4(A);
    wPB[0] = pack_bf16x4(B);
  }
  ldrow(5, pfA[2], pfB[2]);
  ldrow(6, pfA[0], pfB[0]);
  ldrow(7, pfA[1], pfB[1]);
  LGKM_BARRIER();

  // ---- Pass2 identity: output column t (dense stores) ----
  const int jx = t >> 1;
  const int q = t & 1;
  float Lq[4], Hq[4];
#pragma unroll
  for (int s = 0; s < 4; ++s) {
    Lq[s] = q ? Lw[1][s] : Lw[0][s];
    Hq[s] = q ? Hw[1][s] : Hw[0][s];
  }

#pragma unroll
  for (int c = 0; c < RJ; ++c) {
    const int buf = c & 1;

    // ---- Pass2: x-filter j-row c from I[buf] ----
    f32x4 o0 = {0.f, 0.f, 0.f, 0.f};
    f32x4 o1 = {0.f, 0.f, 0.f, 0.f};
#pragma unroll
    for (int s = 0; s < 4; ++s) {
      const int xc = (jx + s) & (N - 1);
      o0 = fma4v(o0, Lq[s], I[buf][0][0][xc]);
      o0 = fma4v(o0, Hq[s], I[buf][0][1][xc]);
      o1 = fma4v(o1, Lq[s], I[buf][1][0][xc]);
      o1 = fma4v(o1, Hq[s], I[buf][1][1][xc]);
    }
    const int jy = r0 + c;
    f32x4* po = ob + (size_t)(2 * jy) * (2 * N) + t;
    po[0] = o0;
    po[2 * N] = o1;

    if (c < RJ - 1) {
      // ---- Pass1: j-row c+1 (uses window rows c+1..c+4) ----
      p1(c + 1, buf ^ 1);
      // Consume prefetched row c+5 (issued 3 steps ago) -> window slot;
      // pack-at-consume = the only vmcnt wait, 3 row-steps after issue.
      if (c <= RJ - 3) {
        const int ps = (c + 5) % 3;
        wPA[(c + 1) & 3] = pack_bf16x4(pfA[ps]);
        wPB[(c + 1) & 3] = pack_bf16x4(pfB[ps]);
      }
      // Issue row c+8 into the slot just freed (consumed at step c+3).
      if (c <= RJ - 6) {
        const int is = (c + 8) % 3;
        ldrow(c + 8, pfA[is], pfB[is]);
      }
      LGKM_BARRIER();
    }
  }
}

extern "C" void kernel_launch(void* const* d_in, const int* in_sizes, int n_in,
                              void* d_out, int out_size, void* d_ws,
                              size_t ws_size, hipStream_t stream) {
  const float* x = reinterpret_cast<const float*>(d_in[0]);
  float* out = reinterpret_cast<float*>(d_out);
  const int grid = 64 * (N / RJ);  // 1024 blocks = 4 per CU
  idwt2_sep13_kernel<<<grid, 512, 0, stream>>>(x, out);
}

// Round 15
// 106.853 us; speedup vs baseline: 1.1471x; 1.0862x over previous
//
#include <hip/hip_runtime.h>

// IDWT2D db4, periodized. Input x: [64][256][256][16] f32 (cA|cH|cV|cD x 4ch),
// output: [64][512][512][4] f32.
//
// R14 = R8 structure with DENSE pass1 loads via lane-pair partial exchange:
// thread t owns input f4 j=t and j=t+512 (pixel p=t>>2, subband-f4 f=t&3)
// -> wave global loads are lane-contiguous 16 B (16 lines/wave-load, was 64:
// 4x line-touch amplification on the TA/L1 path, the last unsaturated pipe).
// y-filter: thread computes both-parity partials with its family weights
// (f even -> Lw for cA/cV, f odd -> Hw for cH/cD), swaps the opposite-parity
// partial with lane t^1 (__shfl_xor), adds -> full intermediate value,
// writes one f4 per column to LDS plane f:
//   plane 0 = par0*lo, 1 = par1*lo, 2 = par0*hi, 3 = par1*hi.
// LDS I[2][4][258] f32x4 (pad 2 -> writes (8f+4p)%32 distinct per 8 lanes,
// reads full bank spread; both conflict-free). Pass2 and dense stores
// identical to R8. 1-row chunks, double-buffer, lgkm-only barrier,
// 4 blocks/CU.

#define N 256
#define RJ 16

typedef float f32x4 __attribute__((ext_vector_type(4)));

// lgkm-only barrier: LDS producer-consumer sync without vmcnt drain.
#define LGKM_BARRIER()                                   \
  do {                                                   \
    asm volatile("s_waitcnt lgkmcnt(0)" ::: "memory");   \
    __builtin_amdgcn_s_barrier();                        \
    asm volatile("" ::: "memory");                       \
  } while (0)

__device__ __forceinline__ f32x4 fma4v(const f32x4 acc, const float s,
                                       const f32x4 a) {
  const f32x4 sv = {s, s, s, s};
  return __builtin_elementwise_fma(a, sv, acc);
}

__device__ __forceinline__ f32x4 shflxor1(const f32x4 v) {
  f32x4 r;
  r.x = __shfl_xor(v.x, 1);
  r.y = __shfl_xor(v.y, 1);
  r.z = __shfl_xor(v.z, 1);
  r.w = __shfl_xor(v.w, 1);
  return r;
}

__global__ __launch_bounds__(512, 4) void idwt2_sep14_kernel(
    const float* __restrict__ x, float* __restrict__ out) {
  constexpr float LO[8] = {
      0.23037781330885523f,  0.7148465705525415f,  0.6308807679295904f,
      -0.02798376941698385f, -0.18703481171888114f, 0.030841381835986965f,
      0.032883011666982945f, -0.010597401784997278f};
  constexpr float HIW[8] = {
      -0.010597401784997278f, -0.032883011666982945f, 0.030841381835986965f,
      0.18703481171888114f,  -0.02798376941698385f,  -0.6308807679295904f,
      0.7148465705525415f,   -0.23037781330885523f};
  const float Lw[2][4] = {{LO[6], LO[4], LO[2], LO[0]},
                          {LO[7], LO[5], LO[3], LO[1]}};
  const float Hw[2][4] = {{HIW[6], HIW[4], HIW[2], HIW[0]},
                          {HIW[7], HIW[5], HIW[3], HIW[1]}};

  // [buf][plane][pixel] f32x4, pixel dim padded 256->258 for bank spread.
  __shared__ f32x4 I[2][4][258];

  const int t = threadIdx.x;
  const int bx = blockIdx.x;
  const int b = bx >> 4;           // 16 consecutive blocks per batch
  const int r0 = (bx & 15) * RJ;

  const f32x4* xb = reinterpret_cast<const f32x4*>(x) + (size_t)b * N * N * 4;
  f32x4* ob = reinterpret_cast<f32x4*>(out) + (size_t)b * (2 * N) * (2 * N);

  // ---- Pass1 identity: f4 index j = t (pixel p, subband-f4 f) + j+512 ----
  const int f = t & 3;
  const int p = t >> 2;  // 0..127; second column is p+128
  const bool fo = f & 1; // false: cA/cV (Lw family), true: cH/cD (Hw family)

  float w_own[4], w_opp[4];  // own-parity / opposite-parity weights
#pragma unroll
  for (int s = 0; s < 4; ++s) {
    w_own[s] = fo ? Hw[1][s] : Lw[0][s];
    w_opp[s] = fo ? Hw[0][s] : Lw[1][s];
  }

  f32x4 w0[4], w1[4], n0, n1;  // sliding windows for columns j=t, j=t+512
  auto ldrow = [&](int lr, f32x4& A, f32x4& B) {
    const int gr = (r0 + lr) & (N - 1);
    const f32x4* xrow = xb + (size_t)gr * (N * 4);
    A = xrow[t];
    B = xrow[t + 512];
  };

  // y-filter local j-row j into I[buf]; window slot (j+sy)&3 holds row j+sy.
  auto p1 = [&](int j, int buf) {
    f32x4 sAo = {0.f, 0.f, 0.f, 0.f}, sAx = {0.f, 0.f, 0.f, 0.f};
    f32x4 sBo = {0.f, 0.f, 0.f, 0.f}, sBx = {0.f, 0.f, 0.f, 0.f};
#pragma unroll
    for (int sy = 0; sy < 4; ++sy) {
      const f32x4 a = w0[(j + sy) & 3];
      const f32x4 bb = w1[(j + sy) & 3];
      sAo = fma4v(sAo, w_own[sy], a);
      sAx = fma4v(sAx, w_opp[sy], a);
      sBo = fma4v(sBo, w_own[sy], bb);
      sBx = fma4v(sBx, w_opp[sy], bb);
    }
    // Exchange opposite-parity partials with lane t^1, add to own.
    const f32x4 vA = sAo + shflxor1(sAx);
    const f32x4 vB = sBo + shflxor1(sBx);
    I[buf][f][p] = vA;
    I[buf][f][p + 128] = vB;
  };

  // Prologue: window rows 0..3, prefetch row 4; p1(0) -> I[0].
#pragma unroll
  for (int m = 0; m < 4; ++m) ldrow(m, w0[m], w1[m]);
  ldrow(4, n0, n1);
  p1(0, 0);
  w0[0] = n0;  // row 4 -> slot 0 (row 0 dead)
  w1[0] = n1;
  ldrow(5, n0, n1);
  LGKM_BARRIER();

  // ---- Pass2 identity: output column t (dense stores) ----
  const int jx = t >> 1;
  const int q = t & 1;
  float Lq[4], Hq[4];
#pragma unroll
  for (int s = 0; s < 4; ++s) {
    Lq[s] = q ? Lw[1][s] : Lw[0][s];
    Hq[s] = q ? Hw[1][s] : Hw[0][s];
  }

#pragma unroll
  for (int c = 0; c < RJ; ++c) {
    const int buf = c & 1;

    // ---- Pass2: x-filter j-row c from I[buf] ----
    // plane 0 = par0*lo, 1 = par1*lo, 2 = par0*hi, 3 = par1*hi
    f32x4 o0 = {0.f, 0.f, 0.f, 0.f};
    f32x4 o1 = {0.f, 0.f, 0.f, 0.f};
#pragma unroll
    for (int s = 0; s < 4; ++s) {
      const int xc = (jx + s) & (N - 1);
      o0 = fma4v(o0, Lq[s], I[buf][0][xc]);
      o0 = fma4v(o0, Hq[s], I[buf][2][xc]);
      o1 = fma4v(o1, Lq[s], I[buf][1][xc]);
      o1 = fma4v(o1, Hq[s], I[buf][3][xc]);
    }
    const int jy = r0 + c;
    f32x4* po = ob + (size_t)(2 * jy) * (2 * N) + t;
    po[0] = o0;
    po[2 * N] = o1;

    if (c < RJ - 1) {
      // ---- Pass1: j-row c+1 (uses window rows c+1..c+4) ----
      p1(c + 1, buf ^ 1);
      // Slide: row c+5 (prefetched, vmcnt-waited here) -> slot (c+1)&3;
      // issue prefetch of row c+6 (stays in flight across the barrier).
      if (c <= RJ - 3) {
        w0[(c + 1) & 3] = n0;
        w1[(c + 1) & 3] = n1;
      }
      if (c <= RJ - 4) ldrow(c + 6, n0, n1);
      LGKM_BARRIER();
    }
  }
}

extern "C" void kernel_launch(void* const* d_in, const int* in_sizes, int n_in,
                              void* d_out, int out_size, void* d_ws,
                              size_t ws_size, hipStream_t stream) {
  const float* x = reinterpret_cast<const float*>(d_in[0]);
  float* out = reinterpret_cast<float*>(d_out);
  const int grid = 64 * (N / RJ);  // 1024 blocks = 4 per CU
  idwt2_sep14_kernel<<<grid, 512, 0, stream>>>(x, out);
}